// Round 17
// baseline (2250.711 us; speedup 1.0000x reference)
//
#include <hip/hip_runtime.h>

// SparseCoding fused persistent kernel, fp32 VALU (R17 = R11 kernel verbatim,
// launch bounds (512,6) -> (512,2)).
// Arithmetic chains bit-identical to R1/R9/R11 (absmax must stay 4.882812e-4).
//
// Clean A/B vs R11: identical code, only the VGPR cap changes (40 -> 128).
// R11 showed 64% occupancy (2x R9) but spilled 1GB scratch under cap 40
// (live state ~70 floats). At cap 128 the state fits -> no spill, keeping:
//  - 512 thr, RTILE=16: phase 2 = ONE column/thread (16 state slots:
//    xs[16], a1[16], a2[16]); phase 1 = 4 rows x 1 col.
//  - W-traffic shape = R9 (W element read once per block per step).
//  - LDS 40 KB (x 32 + d 8) -> 4 blocks/CU; x in regs for update.
//  - step-0 mm1 skipped (x0=0 -> d0 = 0-inp bit-exact).
// Gate: WRITE_SIZE must be 65536 KB exactly (no spill). If dur >= 1600 with
// high occupancy + no spill: stall is structural, restore R9 next round.

#define BSZ   32768
#define DIN   128
#define DOUT  512
#define RTILE 16
#define NSTEP 10
#define NT    512
#define NBLOCKS (BSZ / RTILE)   // 2048

// pack both layouts (one-time, 256 KB each into ws)
__global__ void sc_pack(const float* __restrict__ W, float* __restrict__ W4,
                        float* __restrict__ Wt4) {
    const int tid = blockIdx.x * blockDim.x + threadIdx.x;  // 0..65535
    const int j = tid >> 7;      // 0..511 (coalesced read of W row-major)
    const int i = tid & 127;     // 0..127
    const float v = W[j * DIN + i];
    W4 [(j >> 2) * 512  + i * 4 + (j & 3)] = v;   // [j/4][i][j%4]
    Wt4[(i >> 2) * 2048 + j * 4 + (i & 3)] = v;   // [i/4][j][i%4]
}

__global__ __launch_bounds__(NT, 2)
void sc_fused(const float* __restrict__ inp, const float4* __restrict__ W4,
              const float4* __restrict__ Wt4, float* __restrict__ out)
{
    __shared__ float x_lds[RTILE][DOUT];    // 32 KB
    __shared__ float d_lds[RTILE][DIN];     //  8 KB  (total 40 KB)

    const int t = threadIdx.x;
    const int row0 = blockIdx.x * RTILE;

    const int i_p1 = t & 127;        // phase-1 column (0..127)
    const int rg   = (t >> 7) * 4;   // phase-1 row group {0,4,8,12}
    const int j0   = t;              // phase-2/update column (0..511)

    // phase-2 per-thread state: one column, 16 rows
    float xs[RTILE], a1[RTILE], a2[RTILE];
#pragma unroll
    for (int r = 0; r < RTILE; ++r) { xs[r] = 0.f; a1[r] = 0.f; a2[r] = 0.f; }

    // inp values this thread needs in phase 1 (registers)
    float inr[4];
#pragma unroll
    for (int rr = 0; rr < 4; ++rr)
        inr[rr] = inp[(row0 + rg + rr) * DIN + i_p1];

    // thread-fixed base pointers
    const float4* __restrict__ w4p  = W4 + i_p1;    // + jb*128
    const float4* __restrict__ wt4p = Wt4 + j0;     // + ib*512

    for (int step = 0; step < NSTEP; ++step) {
        // ---- phase 1: d = x @ W - inp ----
        if (step == 0) {
            // x0 = 0: acc chain is exactly 0 -> d = 0 - inp (bit-identical)
#pragma unroll
            for (int rr = 0; rr < 4; ++rr)
                d_lds[rg + rr][i_p1] = 0.0f - inr[rr];
        } else {
            float acc[4];
#pragma unroll
            for (int rr = 0; rr < 4; ++rr) acc[rr] = 0.f;

#pragma unroll 2
            for (int jb = 0; jb < DOUT / 4; ++jb) {
                const float4 wv = w4p[jb * 128];   // W[4jb..4jb+3][i_p1]
#pragma unroll
                for (int rr = 0; rr < 4; ++rr) {
                    const float4 xv = *(const float4*)&x_lds[rg + rr][jb * 4];
                    acc[rr] = fmaf(xv.x, wv.x, acc[rr]);
                    acc[rr] = fmaf(xv.y, wv.y, acc[rr]);
                    acc[rr] = fmaf(xv.z, wv.z, acc[rr]);
                    acc[rr] = fmaf(xv.w, wv.w, acc[rr]);
                }
            }
#pragma unroll
            for (int rr = 0; rr < 4; ++rr)
                d_lds[rg + rr][i_p1] = acc[rr] - inr[rr];
        }
        __syncthreads();

        // ---- phase 2: gacc = d @ W^T (one column j0 per thread) ----
        {
            float acc2[RTILE];
#pragma unroll
            for (int r = 0; r < RTILE; ++r) acc2[r] = 0.f;

#pragma unroll 2
            for (int ib = 0; ib < DIN / 4; ++ib) {
                const float4 wq = wt4p[ib * 512];   // W[j0][4ib..4ib+3]
#pragma unroll
                for (int r = 0; r < RTILE; ++r) {
                    const float4 dv = *(const float4*)&d_lds[r][ib * 4];
                    acc2[r] = fmaf(dv.x, wq.x, acc2[r]);
                    acc2[r] = fmaf(dv.y, wq.y, acc2[r]);
                    acc2[r] = fmaf(dv.z, wq.z, acc2[r]);
                    acc2[r] = fmaf(dv.w, wq.w, acc2[r]);
                }
            }

            // RMSProp + momentum update (x in registers), write x_lds for
            // phase 1 of the next step
#pragma unroll
            for (int r = 0; r < RTILE; ++r) {
                const float xv  = xs[r];
                const float g   = 2.f * acc2[r] + 0.1f * xv * rsqrtf(xv * xv + 1e-6f);
                const float na1 = 0.9f * a1[r] + 0.1f * g * g;
                a1[r] = na1;
                const float upd = 0.001f * g * rsqrtf(na1 + 1e-8f);
                const float na2 = 0.9f * a2[r] - upd;
                a2[r] = na2;
                const float xn = xv + 0.9f * na2 - upd;
                xs[r] = xn;
                x_lds[r][j0] = xn;
            }
            __syncthreads();
        }
    }

    // write final x (coalesced; x_lds holds the final state)
    for (int k = t; k < RTILE * DOUT; k += NT)
        out[row0 * DOUT + k] = (&x_lds[0][0])[k];
}

extern "C" void kernel_launch(void* const* d_in, const int* in_sizes, int n_in,
                              void* d_out, int out_size, void* d_ws, size_t ws_size,
                              hipStream_t stream) {
    const float* inputs = (const float*)d_in[0];
    const float* W      = (const float*)d_in[1];
    float* out          = (float*)d_out;
    float* W4           = (float*)d_ws;               // 256 KB
    float* Wt4          = (float*)d_ws + 65536;       // 256 KB

    sc_pack<<<dim3(256), dim3(256), 0, stream>>>(W, W4, Wt4);
    sc_fused<<<dim3(NBLOCKS), dim3(NT), 0, stream>>>(inputs, (const float4*)W4,
                                                     (const float4*)Wt4, out);
}

// Round 18
// 1602.465 us; speedup vs baseline: 1.4045x; 1.4045x over previous
//
#include <hip/hip_runtime.h>

// SparseCoding fused persistent kernel, fp32 VALU — FINAL (R18 = R9/R16 verbatim).
//
// Session ledger (dur_us):
//   R1  naive fused fp32                    2059   (baseline, absmax 4.9e-4)
//   R3-R8 MFMA split-precision variants     FAIL   (2.4-3.3e-3 > 2e-3; chaotic)
//   R9  = R1 + W^T pack + (256,3)           1606   <- optimum
//   R10 packs + (256,4)                     1640   (spill)
//   R11 512thr 1-col (512,6)                1973   (1GB scratch)
//   R12 packs + col-block                   1798   (spill + L2 thrash)
//   R13 512thr reg-block                    2174   (W L2 traffic x3.5)
//   R14 packs + step0 peel                  1787   (code size / I-cache)
//   R15 inp->regs (256,2)                   1872   (worse allocator schedule)
//   R16 = R9 verbatim                       1605   (anchor reproduced)
//   R17 = R11 @ (512,2), no spill           2250   (occupancy fell; structural)
// Conclusion: R9's ~29% no-issue stall is structural (intra-wave dependency +
// barrier phases); not curable by occupancy/packing/peeling/blocking. The
// MFMA path cannot meet the 2e-3 threshold on this chaotic RMSProp trajectory.
//
// Structure: one block owns 16 rows for all 10 steps; x in LDS, a1/a2 in
// registers; W streamed (L2-resident); phase 2 reads pre-packed fp32 W^T
// (value-identical -> arithmetic bit-identical to the naive fp32 chain).

#define BSZ   32768
#define DIN   128
#define DOUT  512
#define RTILE 16
#define NSTEP 10
#define NBLOCKS (BSZ / RTILE)   // 2048

typedef __attribute__((ext_vector_type(2))) float f32x2;

// pack W^T fp32 into ws: Wt[i][j] = W[j][i]
__global__ void sc_packT(const float* __restrict__ W, float* __restrict__ Wt) {
    const int tid = blockIdx.x * blockDim.x + threadIdx.x;  // 0..65535
    const int j = tid >> 7;      // 0..511 (coalesced read of W row-major)
    const int i = tid & 127;     // 0..127
    Wt[i * DOUT + j] = W[j * DIN + i];
}

__global__ __launch_bounds__(256, 3)
void sc_fused(const float* __restrict__ inp, const float* __restrict__ W,
              const float* __restrict__ Wt, float* __restrict__ out)
{
    __shared__ float x_lds[RTILE][DOUT];    // 32 KB
    __shared__ float d_lds[RTILE][DIN];     //  8 KB
    __shared__ float inp_lds[RTILE][DIN];   //  8 KB

    const int t = threadIdx.x;
    const int row0 = blockIdx.x * RTILE;

    // Per-thread RMSProp state for slots (r, j0), (r, j0+1), r = 0..15
    float a1[RTILE][2];
    float a2[RTILE][2];
#pragma unroll
    for (int r = 0; r < RTILE; ++r) {
        a1[r][0] = a1[r][1] = 0.f;
        a2[r][0] = a2[r][1] = 0.f;
    }

    // init x = 0, load inputs tile (coalesced)
    for (int k = t; k < RTILE * DOUT; k += 256) (&x_lds[0][0])[k] = 0.f;
    for (int k = t; k < RTILE * DIN;  k += 256) (&inp_lds[0][0])[k] = inp[row0 * DIN + k];
    __syncthreads();

    const int i_p1 = t & 127;        // phase-1 column (0..127)
    const int rg   = (t >> 7) * 8;   // phase-1 row group (0 or 8)
    const int j0   = 2 * t;          // phase-2/update column pair (0..510)

    // thread-fixed base pointers (helps SGPR-base + imm-offset codegen)
    const float* __restrict__ wcol = W + i_p1;           // W[j][i_p1] = wcol[j*DIN]
    const float* __restrict__ wtj  = Wt + j0;            // Wt[i][j0]  = wtj[i*DOUT]

    for (int step = 0; step < NSTEP; ++step) {
        // ---- phase 1: d = x @ W - inp  (serial j-chain, identical to R1) ----
        {
            float acc[8];
#pragma unroll
            for (int rr = 0; rr < 8; ++rr) acc[rr] = 0.f;

#pragma unroll 2
            for (int j = 0; j < DOUT; j += 4) {
                const float w0 = wcol[(j + 0) * DIN];
                const float w1 = wcol[(j + 1) * DIN];
                const float w2 = wcol[(j + 2) * DIN];
                const float w3 = wcol[(j + 3) * DIN];
#pragma unroll
                for (int rr = 0; rr < 8; ++rr) {
                    const float4 xv = *(const float4*)&x_lds[rg + rr][j];  // LDS broadcast
                    acc[rr] = fmaf(xv.x, w0, acc[rr]);
                    acc[rr] = fmaf(xv.y, w1, acc[rr]);
                    acc[rr] = fmaf(xv.z, w2, acc[rr]);
                    acc[rr] = fmaf(xv.w, w3, acc[rr]);
                }
            }
#pragma unroll
            for (int rr = 0; rr < 8; ++rr)
                d_lds[rg + rr][i_p1] = acc[rr] - inp_lds[rg + rr][i_p1];
        }
        __syncthreads();

        // ---- phase 2: gacc = d @ W^T (serial i-chain, identical to R1) ----
        {
            float acc[RTILE][2];
#pragma unroll
            for (int r = 0; r < RTILE; ++r) acc[r][0] = acc[r][1] = 0.f;

#pragma unroll 2
            for (int i = 0; i < DIN; i += 4) {
                const f32x2 wq0 = *(const f32x2*)&wtj[(i + 0) * DOUT];
                const f32x2 wq1 = *(const f32x2*)&wtj[(i + 1) * DOUT];
                const f32x2 wq2 = *(const f32x2*)&wtj[(i + 2) * DOUT];
                const f32x2 wq3 = *(const f32x2*)&wtj[(i + 3) * DOUT];
#pragma unroll
                for (int r = 0; r < RTILE; ++r) {
                    const float4 dv = *(const float4*)&d_lds[r][i];  // LDS broadcast
                    acc[r][0] = fmaf(dv.x, wq0.x, acc[r][0]);
                    acc[r][0] = fmaf(dv.y, wq1.x, acc[r][0]);
                    acc[r][0] = fmaf(dv.z, wq2.x, acc[r][0]);
                    acc[r][0] = fmaf(dv.w, wq3.x, acc[r][0]);
                    acc[r][1] = fmaf(dv.x, wq0.y, acc[r][1]);
                    acc[r][1] = fmaf(dv.y, wq1.y, acc[r][1]);
                    acc[r][1] = fmaf(dv.z, wq2.y, acc[r][1]);
                    acc[r][1] = fmaf(dv.w, wq3.y, acc[r][1]);
                }
            }

            // RMSProp + momentum update (identical to R1), x lives in LDS
#pragma unroll
            for (int r = 0; r < RTILE; ++r) {
#pragma unroll
                for (int c = 0; c < 2; ++c) {
                    const float xv  = x_lds[r][j0 + c];
                    const float g   = 2.f * acc[r][c] + 0.1f * xv * rsqrtf(xv * xv + 1e-6f);
                    const float na1 = 0.9f * a1[r][c] + 0.1f * g * g;
                    a1[r][c] = na1;
                    const float upd = 0.001f * g * rsqrtf(na1 + 1e-8f);
                    const float na2 = 0.9f * a2[r][c] - upd;
                    a2[r][c] = na2;
                    x_lds[r][j0 + c] = xv + 0.9f * na2 - upd;
                }
            }
            __syncthreads();
        }
    }

    // write final x (coalesced)
    for (int k = t; k < RTILE * DOUT; k += 256)
        out[row0 * DOUT + k] = (&x_lds[0][0])[k];
}

extern "C" void kernel_launch(void* const* d_in, const int* in_sizes, int n_in,
                              void* d_out, int out_size, void* d_ws, size_t ws_size,
                              hipStream_t stream) {
    const float* inputs = (const float*)d_in[0];
    const float* W      = (const float*)d_in[1];
    float* out          = (float*)d_out;
    float* Wt           = (float*)d_ws;   // 256 KB fp32 W^T

    sc_packT<<<dim3(256), dim3(256), 0, stream>>>(W, Wt);
    sc_fused<<<dim3(NBLOCKS), dim3(256), 0, stream>>>(inputs, W, Wt, out);
}